// Round 6
// baseline (667.919 us; speedup 1.0000x reference)
//
#include <hip/hip_runtime.h>
#include <hip/hip_bf16.h>

// ---------------- problem constants ----------------
#define HD    1152
#define NHD   16        // heads
#define DH    72        // head dim
#define DHP   80        // padded head dim (5 x 16 for mfma K-chunks)
#define NB    16        // batch
#define SEQ   729
#define SP    736       // seq padded to x32 for K tiles
#define MTOT  (NB*SEQ)  // 11664
#define MPAD  11776     // 92 * 128
#define VROWS 96        // V d-rows padded to 3 x 32
// fold head_dim^-0.5 * log2(e) into Q so softmax runs in exp2 domain
#define QSCALE (0.117851130197757930f * 1.4426950408889634f)

typedef __attribute__((ext_vector_type(8))) short short8;
typedef __attribute__((ext_vector_type(4))) float f32x4;
typedef __attribute__((ext_vector_type(16))) float f32x16;
typedef __attribute__((ext_vector_type(4))) unsigned u32x4;

__device__ __forceinline__ unsigned short f2bf(float x){
  unsigned u = __float_as_uint(x);
  u += 0x7FFFu + ((u >> 16) & 1u);   // RNE
  return (unsigned short)(u >> 16);
}

__device__ __forceinline__ unsigned cvtpk_bf16(float lo, float hi){
  unsigned r;
  asm("v_cvt_pk_bf16_f32 %0, %1, %2" : "=v"(r) : "v"(lo), "v"(hi));
  return r;
}

// ---------------- workspace layout (bytes) ----------------
#define OFF_HSB   ((size_t)0)                    // MPAD*HD*2        = 27131904
#define OFF_WQKV  ((size_t)27131904)             // 3456*HD*2        =  7962624
#define OFF_WO    ((size_t)35094528)             // HD*HD*2          =  2654208
#define OFF_Q     ((size_t)37748736)             // 256*SEQ*DHP*2    = 29859840
#define OFF_K     ((size_t)67608576)             // 256*SP*DHP*2     = 30146560
#define OFF_V     ((size_t)97755136)             // 256*VROWS*SP*2   = 36175872
#define WS_END    ((size_t)133931008)
#define Q_BYTES   ((size_t)29859840)

// ---------------- fp32 -> bf16 convert (hidden states) ----------------
__global__ void cvt_hs_kernel(const float* __restrict__ in,
                              unsigned short* __restrict__ out, int n4){
  int i = blockIdx.x*256 + threadIdx.x;
  if (i >= n4) return;
  float4 v = ((const float4*)in)[i];
  ushort4 o;
  o.x = f2bf(v.x); o.y = f2bf(v.y); o.z = f2bf(v.z); o.w = f2bf(v.w);
  ((ushort4*)out)[i] = o;
}

// ---------------- weight transpose + convert: out[n][k] = bf16(W[k][n]) ----------------
__global__ void wt_cvt_kernel(const float* __restrict__ W,
                              unsigned short* __restrict__ outT){
  __shared__ float t[32][33];
  int k0 = blockIdx.x*32, n0 = blockIdx.y*32;
  int tx = threadIdx.x, ty = threadIdx.y;   // (32, 8)
  #pragma unroll
  for (int j=0;j<32;j+=8) t[ty+j][tx] = W[(size_t)(k0+ty+j)*HD + n0 + tx];
  __syncthreads();
  #pragma unroll
  for (int j=0;j<32;j+=8) outT[(size_t)(n0+ty+j)*HD + k0 + tx] = f2bf(t[tx][ty+j]);
}

// ---------------- bf16 GEMM: C[M][N] = A[M][K] * BT[N][K]^T ----------------
// LDS-FREE direct-fragment GEMM: each wave loads its MFMA fragments straight
// from global (L1/L2-resident tiles), no staging, no barriers. The compiler
// pipelines loads across K-steps freely (register dataflow, immediate offsets).
// MODE 0: O-proj -> fp32 out + bias  (TILES_N = 9)
// MODE 1: QKV    -> scatter to padded Q/K/Vt + bias (TILES_N = 27)
template<int MODE>
__global__ __launch_bounds__(256) void gemm_kernel(
    const unsigned short* __restrict__ A, const unsigned short* __restrict__ BT,
    const float* __restrict__ bias_q, const float* __restrict__ bias_k,
    const float* __restrict__ bias_v,
    float* __restrict__ outF,
    unsigned short* __restrict__ Qp, unsigned short* __restrict__ Kp,
    unsigned short* __restrict__ Vt)
{
  constexpr int TILES_N = (MODE==1) ? 27 : 9;
  constexpr int NBLK = (MPAD/128)*TILES_N;

  // T1: bijective XCD-chunked swizzle (m204)
  int blk;
  {
    int orig = blockIdx.x;
    constexpr int q = NBLK >> 3, r = NBLK & 7;
    int xcd = orig & 7, idx = orig >> 3;
    blk = (xcd < r ? xcd*(q+1) : r*(q+1) + (xcd-r)*q) + idx;
  }
  const int tn = blk % TILES_N, tm = blk / TILES_N;
  const int tid = threadIdx.x, w = tid>>6, l = tid&63;
  const int lr = l&15, lg = l>>4;
  const int wm = w>>1, wn = w&1;

  const f32x4 z4 = {0.f,0.f,0.f,0.f};
  f32x4 acc[4][4];
  #pragma unroll
  for (int i=0;i<4;i++)
    #pragma unroll
    for (int j=0;j<4;j++) acc[i][j] = z4;

  // loop-invariant fragment base pointers (K-offset folds into the 13-bit imm)
  const unsigned short* pA[4];
  const unsigned short* pB[4];
  #pragma unroll
  for (int mi=0;mi<4;mi++) pA[mi] = A  + (size_t)(tm*128 + wm*64 + mi*16 + lr)*HD + lg*8;
  #pragma unroll
  for (int ni=0;ni<4;ni++) pB[ni] = BT + (size_t)(tn*128 + wn*64 + ni*16 + lr)*HD + lg*8;

  #pragma unroll 4
  for (int kb = 0; kb < HD; kb += 32){
    short8 af[4], bfr[4];
    #pragma unroll
    for (int mi=0;mi<4;mi++) af[mi]  = *(const short8*)(pA[mi] + kb);
    #pragma unroll
    for (int ni=0;ni<4;ni++) bfr[ni] = *(const short8*)(pB[ni] + kb);
    __builtin_amdgcn_s_setprio(1);
    #pragma unroll
    for (int mi=0;mi<4;mi++)
      #pragma unroll
      for (int ni=0;ni<4;ni++)
        acc[mi][ni] = __builtin_amdgcn_mfma_f32_16x16x32_bf16(af[mi], bfr[ni], acc[mi][ni], 0, 0, 0);
    __builtin_amdgcn_s_setprio(0);
  }

  if (MODE == 0){
    #pragma unroll
    for (int mi=0;mi<4;mi++){
      #pragma unroll
      for (int j=0;j<4;j++){
        int m = tm*128 + wm*64 + mi*16 + lg*4 + j;
        if (m < MTOT){
          #pragma unroll
          for (int ni=0;ni<4;ni++){
            int n = tn*128 + wn*64 + ni*16 + lr;
            outF[(size_t)m*HD + n] = acc[mi][ni][j] + bias_q[n];
          }
        }
      }
    }
  } else {
    #pragma unroll
    for (int mi=0;mi<4;mi++){
      #pragma unroll
      for (int j=0;j<4;j++){
        int m = tm*128 + wm*64 + mi*16 + lg*4 + j;
        if (m >= MTOT) continue;
        int b = m / SEQ;
        int s = m - b*SEQ;
        #pragma unroll
        for (int ni=0;ni<4;ni++){
          int n = tn*128 + wn*64 + ni*16 + lr;
          int mat = n / HD;
          int c = n - mat*HD;
          int h = c / DH;
          int d = c - h*DH;
          const float* bias = (mat==0) ? bias_q : (mat==1) ? bias_k : bias_v;
          float v = acc[mi][ni][j] + bias[c];
          int bh = b*NHD + h;
          if (mat == 0)      Qp[(size_t)bh*(SEQ*DHP) + (size_t)s*DHP + d] = f2bf(v*QSCALE);
          else if (mat == 1) Kp[(size_t)bh*(SP*DHP)  + (size_t)s*DHP + d] = f2bf(v);
          else               Vt[(size_t)bh*(VROWS*SP) + (size_t)d*SP + s] = f2bf(v);
        }
      }
    }
  }
}

// ---------------- PV sub-tile: pack P (in-register) -> bf16 frags, 6 MFMAs ----------------
__device__ __forceinline__ void pv_subtile(const f32x16 s, const unsigned short* __restrict__ vcol,
                                           int hi, f32x16 (&o)[3]){
  // s holds P[q][kcol_local] with kcol_local = (r&3)+8*(r>>2)+4*hi  (q = lane&31)
  unsigned A[4], B[4], xA[4], xB[4];
  #pragma unroll
  for (int g=0; g<4; g++){
    A[g]  = cvtpk_bf16(s[4*g+0], s[4*g+1]);
    B[g]  = cvtpk_bf16(s[4*g+2], s[4*g+3]);
    xA[g] = (unsigned)__shfl_xor((int)A[g], 32);
    xB[g] = (unsigned)__shfl_xor((int)B[g], 32);
  }
  __builtin_amdgcn_s_setprio(1);
  #pragma unroll
  for (int ks=0; ks<2; ks++){
    unsigned w0 = hi ? xA[2*ks+1] : A[2*ks];
    unsigned w1 = hi ? xB[2*ks+1] : B[2*ks];
    unsigned w2 = hi ? A[2*ks+1]  : xA[2*ks];
    unsigned w3 = hi ? B[2*ks+1]  : xB[2*ks];
    u32x4 pw = {w0, w1, w2, w3};
    short8 pa = __builtin_bit_cast(short8, pw);
    #pragma unroll
    for (int dt=0; dt<3; dt++){
      short8 vf = *(const short8*)(vcol + (size_t)(dt*32)*SP + ks*16 + hi*8);
      o[dt] = __builtin_amdgcn_mfma_f32_32x32x16_bf16(pa, vf, o[dt], 0, 0, 0);
    }
  }
  __builtin_amdgcn_s_setprio(0);
}

// ---------------- fused attention: 32 q-rows/wave, swapped QK^T, in-register softmax ----------------
__global__ __launch_bounds__(256) void attn_kernel(
    const unsigned short* __restrict__ Qp, const unsigned short* __restrict__ Kp,
    const unsigned short* __restrict__ Vt, unsigned short* __restrict__ ctx)
{
  const int blk = blockIdx.x;            // 0..1535
  const int xcd = blk & 7, ii = blk >> 3;
  const int bh  = xcd*32 + ii/6;         // 6 consecutive same-XCD blocks share one bh -> L2 reuse
  const int qt6 = ii % 6;
  const int tid = threadIdx.x, w = tid>>6, l = tid&63;
  const int lane = l & 31, hi = l >> 5;

  const int qbase = (qt6*4 + w)*32;
  if (qbase >= SEQ) return;              // wave-uniform; no barriers in this kernel

  const unsigned short* Qb = Qp + (size_t)bh*(SEQ*DHP);
  const unsigned short* Kb = Kp + (size_t)bh*(SP*DHP);
  const unsigned short* Vb = Vt + (size_t)bh*(VROWS*SP);

  int qr = qbase + lane; if (qr > SEQ-1) qr = SEQ-1;
  short8 qf[5];
  #pragma unroll
  for (int c=0;c<5;c++) qf[c] = *(const short8*)(Qb + (size_t)qr*DHP + c*16 + hi*8);

  f32x16 o[3];
  #pragma unroll
  for (int dt=0; dt<3; dt++)
    #pragma unroll
    for (int r=0;r<16;r++) o[dt][r] = 0.f;

  float m = -1e30f, lsum = 0.f;

  for (int kt=0; kt<12; kt++){
    const int kb = kt*64;
    f32x16 s0, s1;
    #pragma unroll
    for (int r=0;r<16;r++){ s0[r]=0.f; s1[r]=0.f; }

    const unsigned short* krow0 = Kb + (size_t)(kb + lane)*DHP + hi*8;
    __builtin_amdgcn_s_setprio(1);
    #pragma unroll
    for (int c=0;c<5;c++){
      short8 kf = *(const short8*)(krow0 + c*16);
      s0 = __builtin_amdgcn_mfma_f32_32x32x16_bf16(kf, qf[c], s0, 0, 0, 0);
    }
    __builtin_amdgcn_s_setprio(0);
    if (kt < 11){
      const unsigned short* krow1 = krow0 + 32*DHP;
      __builtin_amdgcn_s_setprio(1);
      #pragma unroll
      for (int c=0;c<5;c++){
        short8 kf = *(const short8*)(krow1 + c*16);
        s1 = __builtin_amdgcn_mfma_f32_32x32x16_bf16(kf, qf[c], s1, 0, 0, 0);
      }
      __builtin_amdgcn_s_setprio(0);
    } else {
      #pragma unroll
      for (int r=0;r<16;r++){
        const int base = 704 + (r&3) + 8*(r>>2);
        s0[r] = (base + 4*hi >= SEQ) ? -1e30f : s0[r];
        s1[r] = -1e30f;
      }
    }

    float tmax = -1e30f;
    #pragma unroll
    for (int r=0;r<16;r++) tmax = fmaxf(tmax, fmaxf(s0[r], s1[r]));
    tmax = fmaxf(tmax, __shfl_xor(tmax, 32));

    if (!__all(tmax <= m + 8.0f)){       // T13 defer-max (exp2 domain, THR=8)
      float mn = fmaxf(m, tmax);
      float sc = exp2f(m - mn);
      m = mn;
      lsum *= sc;
      #pragma unroll
      for (int dt=0; dt<3; dt++)
        #pragma unroll
        for (int r=0;r<16;r++) o[dt][r] *= sc;
    }

    float su = 0.f;
    #pragma unroll
    for (int r=0;r<16;r++){ float p = exp2f(s0[r]-m); s0[r]=p; su += p; }
    #pragma unroll
    for (int r=0;r<16;r++){ float p = exp2f(s1[r]-m); s1[r]=p; su += p; }
    su += __shfl_xor(su, 32);
    lsum += su;

    const unsigned short* vcol = Vb + (size_t)lane*SP + kb;
    pv_subtile(s0, vcol, hi, o);
    if (kt < 11) pv_subtile(s1, vcol + 32, hi, o);
  }

  float linv = 1.0f / lsum;
  const int b = bh >> 4, h = bh & 15;
  #pragma unroll
  for (int r=0;r<16;r++){
    const int qloc = (r&3) + 8*(r>>2) + 4*hi;
    float lv = __shfl(linv, qloc);
    int q = qbase + qloc;
    if (q < SEQ){
      unsigned short* crow = ctx + ((size_t)(b*SEQ + q))*HD + h*DH;
      #pragma unroll
      for (int dt=0; dt<3; dt++){
        int d = dt*32 + lane;
        if (d < DH) crow[d] = f2bf(o[dt][r] * lv);
      }
    }
  }
}

// ---------------- launcher ----------------
extern "C" void kernel_launch(void* const* d_in, const int* in_sizes, int n_in,
                              void* d_out, int out_size, void* d_ws, size_t ws_size,
                              hipStream_t stream) {
  const float* hs = (const float*)d_in[0];
  const float* Wq = (const float*)d_in[1]; const float* bq = (const float*)d_in[2];
  const float* Wk = (const float*)d_in[3]; const float* bk = (const float*)d_in[4];
  const float* Wv = (const float*)d_in[5]; const float* bv = (const float*)d_in[6];
  const float* Wo = (const float*)d_in[7]; const float* bo = (const float*)d_in[8];
  float* out = (float*)d_out;
  char* ws = (char*)d_ws;
  if (ws_size < WS_END) return;

  unsigned short* hsb   = (unsigned short*)(ws + OFF_HSB);  // later reused as ctx
  unsigned short* wqkvT = (unsigned short*)(ws + OFF_WQKV);
  unsigned short* woT   = (unsigned short*)(ws + OFF_WO);
  unsigned short* Qp    = (unsigned short*)(ws + OFF_Q);
  unsigned short* Kp    = (unsigned short*)(ws + OFF_K);
  unsigned short* Vt    = (unsigned short*)(ws + OFF_V);
  unsigned short* ctx   = hsb;

  // 1. convert hidden states to bf16
  int n4 = MTOT*HD/4;
  cvt_hs_kernel<<<(n4+255)/256, 256, 0, stream>>>(hs, hsb, n4);

  // 2. weights: transpose + convert to bf16 (n-major)
  dim3 bt(32, 8), gt(HD/32, HD/32);
  wt_cvt_kernel<<<gt, bt, 0, stream>>>(Wq, wqkvT);
  wt_cvt_kernel<<<gt, bt, 0, stream>>>(Wk, wqkvT + (size_t)HD*HD);
  wt_cvt_kernel<<<gt, bt, 0, stream>>>(Wv, wqkvT + (size_t)2*HD*HD);
  wt_cvt_kernel<<<gt, bt, 0, stream>>>(Wo, woT);

  // 3. zero Q only (its d-pads 72..79 must be 0 so K's garbage pads contribute 0;
  //    K s-pad rows are masked, V pad cols multiply p==0)
  hipMemsetAsync(ws + OFF_Q, 0, Q_BYTES, stream);

  // 4. QKV projection GEMM, scatter epilogue (Q pre-scaled by SCALE*log2e)
  gemm_kernel<1><<<(MPAD/128)*27, 256, 0, stream>>>(hsb, wqkvT, bq, bk, bv,
                                                    nullptr, Qp, Kp, Vt);

  // 5. fused attention -> ctx [MTOT][1152] bf16 (reuses hsb buffer)
  attn_kernel<<<1536, 256, 0, stream>>>(Qp, Kp, Vt, ctx);

  // 6. output projection GEMM -> fp32 out + bo
  gemm_kernel<0><<<(MPAD/128)*9, 256, 0, stream>>>(ctx, woT, bo, nullptr, nullptr,
                                                   out, nullptr, nullptr, nullptr);
}

// Round 7
// 496.244 us; speedup vs baseline: 1.3459x; 1.3459x over previous
//
#include <hip/hip_runtime.h>
#include <hip/hip_bf16.h>

// ---------------- problem constants ----------------
#define HD    1152
#define NHD   16        // heads
#define DH    72        // head dim
#define DHP   80        // padded head dim (5 x 16 for mfma K-chunks)
#define NB    16        // batch
#define SEQ   729
#define SP    736       // seq padded to x32 for K tiles
#define MTOT  (NB*SEQ)  // 11664
#define MPAD  11776     // 46 * 256
#define VROWS 96        // V d-rows padded to 3 x 32
#define NQKV  3456
// fold head_dim^-0.5 * log2(e) into Q so softmax runs in exp2 domain
#define QSCALE (0.117851130197757930f * 1.4426950408889634f)

typedef __attribute__((ext_vector_type(8))) short short8;
typedef __attribute__((ext_vector_type(4))) float f32x4;
typedef __attribute__((ext_vector_type(16))) float f32x16;
typedef __attribute__((ext_vector_type(4))) unsigned u32x4;
typedef unsigned short us;

__device__ __forceinline__ us f2bf(float x){
  unsigned u = __float_as_uint(x);
  u += 0x7FFFu + ((u >> 16) & 1u);   // RNE
  return (us)(u >> 16);
}

__device__ __forceinline__ unsigned cvtpk_bf16(float lo, float hi){
  unsigned r;
  asm("v_cvt_pk_bf16_f32 %0, %1, %2" : "=v"(r) : "v"(lo), "v"(hi));
  return r;
}

#define GLD16(g, s) __builtin_amdgcn_global_load_lds( \
    (const __attribute__((address_space(1))) void*)(g), \
    (__attribute__((address_space(3))) void*)(s), 16, 0, 0)

#define BARM  asm volatile("s_barrier" ::: "memory")
#define VMC4  asm volatile("s_waitcnt vmcnt(4)" ::: "memory")

// ---------------- workspace layout (bytes) ----------------
// NOTE: GEMM N-pad reads intentionally spill into the NEXT buffer (allocated,
// garbage OK, masked at write). wqkvT pad rows 3456..3583 -> woT region;
// woT pad rows 1152..1279 -> Q region.
#define OFF_HSB   ((size_t)0)                    // MPAD*HD*2        = 27131904
#define OFF_WQKV  ((size_t)27131904)             // 3456*HD*2        =  7962624
#define OFF_WO    ((size_t)35094528)             // HD*HD*2          =  2654208
#define OFF_Q     ((size_t)37748736)             // 256*SEQ*DHP*2    = 29859840
#define OFF_K     ((size_t)67608576)             // 256*SP*DHP*2     = 30146560
#define OFF_V     ((size_t)97755136)             // 256*VROWS*SP*2   = 36175872
#define WS_END    ((size_t)133931008)
#define Q_BYTES   ((size_t)29859840)

// ---------------- fp32 -> bf16 convert (hidden states) ----------------
__global__ void cvt_hs_kernel(const float* __restrict__ in,
                              us* __restrict__ out, int n4){
  int i = blockIdx.x*256 + threadIdx.x;
  if (i >= n4) return;
  float4 v = ((const float4*)in)[i];
  ushort4 o;
  o.x = f2bf(v.x); o.y = f2bf(v.y); o.z = f2bf(v.z); o.w = f2bf(v.w);
  ((ushort4*)out)[i] = o;
}

// ---------------- weight transpose + convert: out[n][k] = bf16(W[k][n]) ----------------
__global__ void wt_cvt_kernel(const float* __restrict__ W,
                              us* __restrict__ outT){
  __shared__ float t[32][33];
  int k0 = blockIdx.x*32, n0 = blockIdx.y*32;
  int tx = threadIdx.x, ty = threadIdx.y;   // (32, 8)
  #pragma unroll
  for (int j=0;j<32;j+=8) t[ty+j][tx] = W[(size_t)(k0+ty+j)*HD + n0 + tx];
  __syncthreads();
  #pragma unroll
  for (int j=0;j<32;j+=8) outT[(size_t)(n0+ty+j)*HD + k0 + tx] = f2bf(t[tx][ty+j]);
}

// ---------------- 256x256 8-phase bf16 GEMM: C = A[M][K] * BT[N][K]^T ----------------
// 8 waves (2M x 4N), BK=64, 2 K-tiles/iter, 8 phases/iter, counted vmcnt(4)
// at phases 4 & 8 only. LDS 128 KiB dbuf. Bit-6 XOR bank swizzle (both-sides).
// MODE 0: O-proj -> fp32 out + bias  (TILES_N=5, N-pad 1280)
// MODE 1: QKV    -> scatter to padded Q/K/Vt + bias (TILES_N=14, N-pad 3584)
template<int MODE>
__global__ __launch_bounds__(512, 2) void gemm256_kernel(
    const us* __restrict__ A, const us* __restrict__ BT,
    const float* __restrict__ bias_q, const float* __restrict__ bias_k,
    const float* __restrict__ bias_v,
    float* __restrict__ outF,
    us* __restrict__ Qp, us* __restrict__ Kp, us* __restrict__ Vt)
{
  constexpr int TILES_N = (MODE==1) ? 14 : 5;
  constexpr int NBLK = 46*TILES_N;
  constexpr int NKT = HD/64;     // 18 K-tiles
  constexpr int NLIM = (MODE==1) ? NQKV : HD;

  // T1: bijective XCD-chunked swizzle (m204)
  int blk;
  {
    int orig = blockIdx.x;
    constexpr int q = NBLK >> 3, r = NBLK & 7;
    int xcd = orig & 7, idx = orig >> 3;
    blk = (xcd < r ? xcd*(q+1) : r*(q+1) + (xcd-r)*q) + idx;
  }
  const int tn = blk % TILES_N, tm = blk / TILES_N;
  const int tid = threadIdx.x;
  const int w = tid>>6, l = tid&63, lr = l&15, lg = l>>4;
  const int wm = w>>2, wn = w&3;        // 2 x 4 wave grid

  __shared__ __align__(16) us As[2][2][8192];   // [slot][half(128 rows)][row*64+col]
  __shared__ __align__(16) us Bs[2][2][8192];

  f32x4 acc[8][4];
  #pragma unroll
  for (int i=0;i<8;i++)
    #pragma unroll
    for (int j=0;j<4;j++) acc[i][j] = (f32x4){0.f,0.f,0.f,0.f};

  // read-side swizzled column offsets (elements): phys col-chunk bit5 ^= row&1 (=lr&1)
  const int colA0 = lg*8 + ((lr&1)<<5);
  const int colA1 = colA0 ^ 32;

  // stage source: thread t covers row trow, source chunk inverse-swizzled
  const int trow = tid>>3;
  const int tch  = ((tid&7) ^ ((trow&1)<<2))*8;
  const us* gAs = A  + (size_t)(tm*256 + trow)*HD + tch;
  const us* gBs = BT + (size_t)(tn*256 + trow)*HD + tch;

#define STG(gbase, Ms, s, k, h) do { \
    GLD16(gbase + ((size_t)((h)*128      ))*HD + (k)*64, &Ms[s][h][w*512]); \
    GLD16(gbase + ((size_t)((h)*128 + 64))*HD + (k)*64, &Ms[s][h][4096 + w*512]); \
  } while(0)

  short8 a_[4][2], b0_[2][2], b1_[2][2];

#define RDA(s, qa) do { \
    _Pragma("unroll") \
    for (int mi=0;mi<4;mi++){ \
      const us* p = &As[s][wm][((qa)*64 + mi*16 + lr)*64]; \
      a_[mi][0] = *(const short8*)(p + colA0); \
      a_[mi][1] = *(const short8*)(p + colA1); } \
  } while(0)

#define RDB(s, qb, breg) do { \
    _Pragma("unroll") \
    for (int ni=0;ni<2;ni++){ \
      const us* p = &Bs[s][wn>>1][((wn&1)*64 + (qb)*32 + ni*16 + lr)*64]; \
      breg[ni][0] = *(const short8*)(p + colA0); \
      breg[ni][1] = *(const short8*)(p + colA1); } \
  } while(0)

#define MM(qa, qb, breg) do { \
    __builtin_amdgcn_s_setprio(1); \
    _Pragma("unroll") \
    for (int mi=0;mi<4;mi++) \
      _Pragma("unroll") \
      for (int ni=0;ni<2;ni++){ \
        acc[(qa)*4+mi][(qb)*2+ni] = __builtin_amdgcn_mfma_f32_16x16x32_bf16(a_[mi][0], breg[ni][0], acc[(qa)*4+mi][(qb)*2+ni],0,0,0); \
        acc[(qa)*4+mi][(qb)*2+ni] = __builtin_amdgcn_mfma_f32_16x16x32_bf16(a_[mi][1], breg[ni][1], acc[(qa)*4+mi][(qb)*2+ni],0,0,0); } \
    __builtin_amdgcn_s_setprio(0); \
  } while(0)

  // prologue: B(0), A(0) -> slot0; B(1) -> slot1   (12 loads; land first 8)
  STG(gBs, Bs, 0, 0, 0); STG(gBs, Bs, 0, 0, 1);
  STG(gAs, As, 0, 0, 0); STG(gAs, As, 0, 0, 1);
  STG(gBs, Bs, 1, 1, 0); STG(gBs, Bs, 1, 1, 1);
  VMC4; BARM;

  for (int k0 = 0; k0 < NKT; k0 += 2){
    const int k1 = k0 + 1;
    const int k2 = (k0+2 < NKT) ? k0+2 : 0;   // tail: dummy re-stage into dead regions
    const int k3 = (k0+3 < NKT) ? k0+3 : 1;
    // ph1: quad(0,0) slot0 | stage A(k1)->slot1 h0
    RDA(0,0); RDB(0,0,b0_); STG(gAs, As, 1, k1, 0); BARM; MM(0,0,b0_); BARM;
    // ph2: quad(0,1) | stage A(k1)->slot1 h1
    RDB(0,1,b1_); STG(gAs, As, 1, k1, 1); BARM; MM(0,1,b1_); BARM;
    // ph3: quad(1,1) | stage B(k2)->slot0 h0
    RDA(0,1); STG(gBs, Bs, 0, k2, 0); BARM; MM(1,1,b1_); BARM;
    // ph4: quad(1,0) | stage B(k2)->slot0 h1 | vmcnt(4)
    STG(gBs, Bs, 0, k2, 1); BARM; MM(1,0,b0_); VMC4; BARM;
    // ph5: quad(0,0) slot1 | stage A(k2)->slot0 h0
    RDA(1,0); RDB(1,0,b0_); STG(gAs, As, 0, k2, 0); BARM; MM(0,0,b0_); BARM;
    // ph6: quad(0,1) | stage A(k2)->slot0 h1
    RDB(1,1,b1_); STG(gAs, As, 0, k2, 1); BARM; MM(0,1,b1_); BARM;
    // ph7: quad(1,1) | stage B(k3)->slot1 h0
    RDA(1,1); STG(gBs, Bs, 1, k3, 0); BARM; MM(1,1,b1_); BARM;
    // ph8: quad(1,0) | stage B(k3)->slot1 h1 | vmcnt(4)
    STG(gBs, Bs, 1, k3, 1); BARM; MM(1,0,b0_); VMC4; BARM;
  }
#undef STG
#undef RDA
#undef RDB
#undef MM

  if (MODE == 0){
    #pragma unroll
    for (int mi=0;mi<8;mi++){
      #pragma unroll
      for (int j=0;j<4;j++){
        int m = tm*256 + wm*128 + mi*16 + lg*4 + j;
        if (m < MTOT){
          #pragma unroll
          for (int ni=0;ni<4;ni++){
            int n = tn*256 + wn*64 + ni*16 + lr;
            if (n < NLIM) outF[(size_t)m*HD + n] = acc[mi][ni][j] + bias_q[n];
          }
        }
      }
    }
  } else {
    #pragma unroll
    for (int mi=0;mi<8;mi++){
      #pragma unroll
      for (int j=0;j<4;j++){
        int m = tm*256 + wm*128 + mi*16 + lg*4 + j;
        if (m >= MTOT) continue;
        int b = m / SEQ;
        int s = m - b*SEQ;
        #pragma unroll
        for (int ni=0;ni<4;ni++){
          int n = tn*256 + wn*64 + ni*16 + lr;
          if (n >= NLIM) continue;
          int mat = n / HD;
          int c = n - mat*HD;
          int h = c / DH;
          int d = c - h*DH;
          const float* bias = (mat==0) ? bias_q : (mat==1) ? bias_k : bias_v;
          float v = acc[mi][ni][j] + bias[c];
          int bh = b*NHD + h;
          if (mat == 0)      Qp[(size_t)bh*(SEQ*DHP) + (size_t)s*DHP + d] = f2bf(v*QSCALE);
          else if (mat == 1) Kp[(size_t)bh*(SP*DHP)  + (size_t)s*DHP + d] = f2bf(v);
          else               Vt[(size_t)bh*(VROWS*SP) + (size_t)d*SP + s] = f2bf(v);
        }
      }
    }
  }
}

// ---------------- PV sub-tile: pack P (in-register) -> bf16 frags, 6 MFMAs ----------------
__device__ __forceinline__ void pv_subtile(const f32x16 s, const us* __restrict__ vcol,
                                           int hi, f32x16 (&o)[3]){
  unsigned A[4], B[4], xA[4], xB[4];
  #pragma unroll
  for (int g=0; g<4; g++){
    A[g]  = cvtpk_bf16(s[4*g+0], s[4*g+1]);
    B[g]  = cvtpk_bf16(s[4*g+2], s[4*g+3]);
    xA[g] = (unsigned)__shfl_xor((int)A[g], 32);
    xB[g] = (unsigned)__shfl_xor((int)B[g], 32);
  }
  __builtin_amdgcn_s_setprio(1);
  #pragma unroll
  for (int ks=0; ks<2; ks++){
    unsigned w0 = hi ? xA[2*ks+1] : A[2*ks];
    unsigned w1 = hi ? xB[2*ks+1] : B[2*ks];
    unsigned w2 = hi ? A[2*ks+1]  : xA[2*ks];
    unsigned w3 = hi ? B[2*ks+1]  : xB[2*ks];
    u32x4 pw = {w0, w1, w2, w3};
    short8 pa = __builtin_bit_cast(short8, pw);
    #pragma unroll
    for (int dt=0; dt<3; dt++){
      short8 vf = *(const short8*)(vcol + (size_t)(dt*32)*SP + ks*16 + hi*8);
      o[dt] = __builtin_amdgcn_mfma_f32_32x32x16_bf16(pa, vf, o[dt], 0, 0, 0);
    }
  }
  __builtin_amdgcn_s_setprio(0);
}

// ---------------- fused attention: 32 q-rows/wave, swapped QK^T, in-register softmax ----------------
__global__ __launch_bounds__(256) void attn_kernel(
    const us* __restrict__ Qp, const us* __restrict__ Kp,
    const us* __restrict__ Vt, us* __restrict__ ctx)
{
  const int blk = blockIdx.x;            // 0..1535
  const int xcd = blk & 7, ii = blk >> 3;
  const int bh  = xcd*32 + ii/6;
  const int qt6 = ii % 6;
  const int tid = threadIdx.x, w = tid>>6, l = tid&63;
  const int lane = l & 31, hi = l >> 5;

  const int qbase = (qt6*4 + w)*32;
  if (qbase >= SEQ) return;

  const us* Qb = Qp + (size_t)bh*(SEQ*DHP);
  const us* Kb = Kp + (size_t)bh*(SP*DHP);
  const us* Vb = Vt + (size_t)bh*(VROWS*SP);

  int qr = qbase + lane; if (qr > SEQ-1) qr = SEQ-1;
  short8 qf[5];
  #pragma unroll
  for (int c=0;c<5;c++) qf[c] = *(const short8*)(Qb + (size_t)qr*DHP + c*16 + hi*8);

  f32x16 o[3];
  #pragma unroll
  for (int dt=0; dt<3; dt++)
    #pragma unroll
    for (int r=0;r<16;r++) o[dt][r] = 0.f;

  float m = -1e30f, lsum = 0.f;

  for (int kt=0; kt<12; kt++){
    const int kb = kt*64;
    f32x16 s0, s1;
    #pragma unroll
    for (int r=0;r<16;r++){ s0[r]=0.f; s1[r]=0.f; }

    const us* krow0 = Kb + (size_t)(kb + lane)*DHP + hi*8;
    __builtin_amdgcn_s_setprio(1);
    #pragma unroll
    for (int c=0;c<5;c++){
      short8 kf = *(const short8*)(krow0 + c*16);
      s0 = __builtin_amdgcn_mfma_f32_32x32x16_bf16(kf, qf[c], s0, 0, 0, 0);
    }
    __builtin_amdgcn_s_setprio(0);
    if (kt < 11){
      const us* krow1 = krow0 + 32*DHP;
      __builtin_amdgcn_s_setprio(1);
      #pragma unroll
      for (int c=0;c<5;c++){
        short8 kf = *(const short8*)(krow1 + c*16);
        s1 = __builtin_amdgcn_mfma_f32_32x32x16_bf16(kf, qf[c], s1, 0, 0, 0);
      }
      __builtin_amdgcn_s_setprio(0);
    } else {
      #pragma unroll
      for (int r=0;r<16;r++){
        const int base = 704 + (r&3) + 8*(r>>2);
        s0[r] = (base + 4*hi >= SEQ) ? -1e30f : s0[r];
        s1[r] = -1e30f;
      }
    }

    float tmax = -1e30f;
    #pragma unroll
    for (int r=0;r<16;r++) tmax = fmaxf(tmax, fmaxf(s0[r], s1[r]));
    tmax = fmaxf(tmax, __shfl_xor(tmax, 32));

    if (!__all(tmax <= m + 8.0f)){       // T13 defer-max (exp2 domain, THR=8)
      float mn = fmaxf(m, tmax);
      float sc = exp2f(m - mn);
      m = mn;
      lsum *= sc;
      #pragma unroll
      for (int dt=0; dt<3; dt++)
        #pragma unroll
        for (int r=0;r<16;r++) o[dt][r] *= sc;
    }

    float su = 0.f;
    #pragma unroll
    for (int r=0;r<16;r++){ float p = exp2f(s0[r]-m); s0[r]=p; su += p; }
    #pragma unroll
    for (int r=0;r<16;r++){ float p = exp2f(s1[r]-m); s1[r]=p; su += p; }
    su += __shfl_xor(su, 32);
    lsum += su;

    const us* vcol = Vb + (size_t)lane*SP + kb;
    pv_subtile(s0, vcol, hi, o);
    if (kt < 11) pv_subtile(s1, vcol + 32, hi, o);
  }

  float linv = 1.0f / lsum;
  const int b = bh >> 4, h = bh & 15;
  #pragma unroll
  for (int r=0;r<16;r++){
    const int qloc = (r&3) + 8*(r>>2) + 4*hi;
    float lv = __shfl(linv, qloc);
    int q = qbase + qloc;
    if (q < SEQ){
      us* crow = ctx + ((size_t)(b*SEQ + q))*HD + h*DH;
      #pragma unroll
      for (int dt=0; dt<3; dt++){
        int d = dt*32 + lane;
        if (d < DH) crow[d] = f2bf(o[dt][r] * lv);
      }
    }
  }
}

// ---------------- launcher ----------------
extern "C" void kernel_launch(void* const* d_in, const int* in_sizes, int n_in,
                              void* d_out, int out_size, void* d_ws, size_t ws_size,
                              hipStream_t stream) {
  const float* hs = (const float*)d_in[0];
  const float* Wq = (const float*)d_in[1]; const float* bq = (const float*)d_in[2];
  const float* Wk = (const float*)d_in[3]; const float* bk = (const float*)d_in[4];
  const float* Wv = (const float*)d_in[5]; const float* bv = (const float*)d_in[6];
  const float* Wo = (const float*)d_in[7]; const float* bo = (const float*)d_in[8];
  float* out = (float*)d_out;
  char* ws = (char*)d_ws;
  if (ws_size < WS_END) return;

  us* hsb   = (us*)(ws + OFF_HSB);  // later reused as ctx
  us* wqkvT = (us*)(ws + OFF_WQKV);
  us* woT   = (us*)(ws + OFF_WO);
  us* Qp    = (us*)(ws + OFF_Q);
  us* Kp    = (us*)(ws + OFF_K);
  us* Vt    = (us*)(ws + OFF_V);
  us* ctx   = hsb;

  // 1. convert hidden states to bf16
  int n4 = MTOT*HD/4;
  cvt_hs_kernel<<<(n4+255)/256, 256, 0, stream>>>(hs, hsb, n4);

  // 2. weights: transpose + convert to bf16 (n-major)
  dim3 bt(32, 8), gt(HD/32, HD/32);
  wt_cvt_kernel<<<gt, bt, 0, stream>>>(Wq, wqkvT);
  wt_cvt_kernel<<<gt, bt, 0, stream>>>(Wk, wqkvT + (size_t)HD*HD);
  wt_cvt_kernel<<<gt, bt, 0, stream>>>(Wv, wqkvT + (size_t)2*HD*HD);
  wt_cvt_kernel<<<gt, bt, 0, stream>>>(Wo, woT);

  // 3. zero Q only (d-pads 72..79 must be 0 vs K's garbage pads)
  hipMemsetAsync(ws + OFF_Q, 0, Q_BYTES, stream);

  // 4. QKV projection GEMM (256x256 8-phase), scatter epilogue
  gemm256_kernel<1><<<46*14, 512, 0, stream>>>(hsb, wqkvT, bq, bk, bv,
                                               nullptr, Qp, Kp, Vt);

  // 5. fused attention -> ctx [MTOT][1152] bf16 (reuses hsb buffer)
  attn_kernel<<<1536, 256, 0, stream>>>(Qp, Kp, Vt, ctx);

  // 6. output projection GEMM -> fp32 out + bo
  gemm256_kernel<0><<<46*5, 512, 0, stream>>>(ctx, woT, bo, nullptr, nullptr,
                                              out, nullptr, nullptr, nullptr);
}

// Round 8
// 452.352 us; speedup vs baseline: 1.4765x; 1.0970x over previous
//
#include <hip/hip_runtime.h>
#include <hip/hip_bf16.h>

// ---------------- problem constants ----------------
#define HD    1152
#define NHD   16        // heads
#define DH    72        // head dim
#define DHP   80        // padded head dim (5 x 16 for mfma K-chunks)
#define NB    16        // batch
#define SEQ   729
#define SP    736       // seq padded to x32 for K tiles
#define MTOT  (NB*SEQ)  // 11664
#define MPAD  11776     // 46 * 256
#define VROWS 96        // V d-rows padded to 3 x 32
#define NQKV  3456
// fold head_dim^-0.5 * log2(e) into Q so softmax runs in exp2 domain
#define QSCALE (0.117851130197757930f * 1.4426950408889634f)

typedef __attribute__((ext_vector_type(8))) short short8;
typedef __attribute__((ext_vector_type(4))) float f32x4;
typedef __attribute__((ext_vector_type(16))) float f32x16;
typedef __attribute__((ext_vector_type(4))) unsigned u32x4;
typedef unsigned short us;

__device__ __forceinline__ us f2bf(float x){
  unsigned u = __float_as_uint(x);
  u += 0x7FFFu + ((u >> 16) & 1u);   // RNE
  return (us)(u >> 16);
}

__device__ __forceinline__ unsigned cvtpk_bf16(float lo, float hi){
  unsigned r;
  asm("v_cvt_pk_bf16_f32 %0, %1, %2" : "=v"(r) : "v"(lo), "v"(hi));
  return r;
}

#define GLD16(g, s) __builtin_amdgcn_global_load_lds( \
    (const __attribute__((address_space(1))) void*)(g), \
    (__attribute__((address_space(3))) void*)(s), 16, 0, 0)

#define BARM  asm volatile("s_barrier" ::: "memory")
#define VMC4  asm volatile("s_waitcnt vmcnt(4)" ::: "memory")

// ---------------- workspace layout (bytes) ----------------
// NOTE: GEMM N-pad reads intentionally spill into the NEXT buffer (allocated,
// garbage OK, masked at write). wqkvT pad rows 3456..3583 -> woT region;
// woT pad rows 1152..1279 -> Q region.
#define OFF_HSB   ((size_t)0)                    // MPAD*HD*2        = 27131904
#define OFF_WQKV  ((size_t)27131904)             // 3456*HD*2        =  7962624
#define OFF_WO    ((size_t)35094528)             // HD*HD*2          =  2654208
#define OFF_Q     ((size_t)37748736)             // 256*SEQ*DHP*2    = 29859840
#define OFF_K     ((size_t)67608576)             // 256*SP*DHP*2     = 30146560
#define OFF_V     ((size_t)97755136)             // 256*VROWS*SP*2   = 36175872
#define WS_END    ((size_t)133931008)
#define Q_BYTES   ((size_t)29859840)

// ---------------- fp32 -> bf16 convert (hidden states) ----------------
__global__ void cvt_hs_kernel(const float* __restrict__ in,
                              us* __restrict__ out, int n4){
  int i = blockIdx.x*256 + threadIdx.x;
  if (i >= n4) return;
  float4 v = ((const float4*)in)[i];
  ushort4 o;
  o.x = f2bf(v.x); o.y = f2bf(v.y); o.z = f2bf(v.z); o.w = f2bf(v.w);
  ((ushort4*)out)[i] = o;
}

// ---------------- weight transpose + convert: out[n][k] = bf16(W[k][n]) ----------------
__global__ void wt_cvt_kernel(const float* __restrict__ W,
                              us* __restrict__ outT){
  __shared__ float t[32][33];
  int k0 = blockIdx.x*32, n0 = blockIdx.y*32;
  int tx = threadIdx.x, ty = threadIdx.y;   // (32, 8)
  #pragma unroll
  for (int j=0;j<32;j+=8) t[ty+j][tx] = W[(size_t)(k0+ty+j)*HD + n0 + tx];
  __syncthreads();
  #pragma unroll
  for (int j=0;j<32;j+=8) outT[(size_t)(n0+ty+j)*HD + k0 + tx] = f2bf(t[tx][ty+j]);
}

// ---------------- 256x256 8-phase bf16 GEMM: C = A[M][K] * BT[N][K]^T ----------------
// 8 waves (2M x 4N), BK=64, 2 K-tiles/iter, 8 phases/iter, counted vmcnt(4)
// at phases 4 & 8 only. LDS 128 KiB dbuf.
// T2 swizzle (conflict-free ds_read_b128): phys_chunk = chunk ^ (row&7),
// 16-B granularity, applied BOTH-sides: inverse-permuted global source for the
// linear global_load_lds dest + same XOR on the read column (rule #21).
// MODE 0: O-proj -> fp32 out + bias  (TILES_N=5, N-pad 1280)
// MODE 1: QKV    -> scatter to padded Q/K/Vt + bias (TILES_N=14, N-pad 3584)
template<int MODE>
__global__ __launch_bounds__(512, 2) void gemm256_kernel(
    const us* __restrict__ A, const us* __restrict__ BT,
    const float* __restrict__ bias_q, const float* __restrict__ bias_k,
    const float* __restrict__ bias_v,
    float* __restrict__ outF,
    us* __restrict__ Qp, us* __restrict__ Kp, us* __restrict__ Vt)
{
  constexpr int TILES_N = (MODE==1) ? 14 : 5;
  constexpr int NBLK = 46*TILES_N;
  constexpr int NKT = HD/64;     // 18 K-tiles
  constexpr int NLIM = (MODE==1) ? NQKV : HD;

  // T1: bijective XCD-chunked swizzle (m204)
  int blk;
  {
    int orig = blockIdx.x;
    constexpr int q = NBLK >> 3, r = NBLK & 7;
    int xcd = orig & 7, idx = orig >> 3;
    blk = (xcd < r ? xcd*(q+1) : r*(q+1) + (xcd-r)*q) + idx;
  }
  const int tn = blk % TILES_N, tm = blk / TILES_N;
  const int tid = threadIdx.x;
  const int w = tid>>6, l = tid&63, lr = l&15, lg = l>>4;
  const int wm = w>>2, wn = w&3;        // 2 x 4 wave grid

  __shared__ __align__(16) us As[2][2][8192];   // [slot][half(128 rows)][row*64+col]
  __shared__ __align__(16) us Bs[2][2][8192];

  f32x4 acc[8][4];
  #pragma unroll
  for (int i=0;i<8;i++)
    #pragma unroll
    for (int j=0;j<4;j++) acc[i][j] = (f32x4){0.f,0.f,0.f,0.f};

  // read-side swizzle: desired chunk lg (k-half 0) / lg+4 (k-half 1),
  // phys chunk = chunk ^ (row&7); row&7 == lr&7 for every fragment row.
  const int colA0 = (lg ^ (lr&7))*8;
  const int colA1 = colA0 ^ 32;

  // stage source: thread covers LDS (row = trow, phys chunk = tid&7);
  // its CONTENT must be logical chunk (tid&7)^(trow&7) -> pre-swizzled source.
  const int trow = tid>>3;
  const int tch  = ((tid&7) ^ (trow&7))*8;
  const us* gAs = A  + (size_t)(tm*256 + trow)*HD + tch;
  const us* gBs = BT + (size_t)(tn*256 + trow)*HD + tch;

#define STG(gbase, Ms, s, k, h) do { \
    GLD16(gbase + ((size_t)((h)*128      ))*HD + (k)*64, &Ms[s][h][w*512]); \
    GLD16(gbase + ((size_t)((h)*128 + 64))*HD + (k)*64, &Ms[s][h][4096 + w*512]); \
  } while(0)

  short8 a_[4][2], b0_[2][2], b1_[2][2];

#define RDA(s, qa) do { \
    _Pragma("unroll") \
    for (int mi=0;mi<4;mi++){ \
      const us* p = &As[s][wm][((qa)*64 + mi*16 + lr)*64]; \
      a_[mi][0] = *(const short8*)(p + colA0); \
      a_[mi][1] = *(const short8*)(p + colA1); } \
  } while(0)

#define RDB(s, qb, breg) do { \
    _Pragma("unroll") \
    for (int ni=0;ni<2;ni++){ \
      const us* p = &Bs[s][wn>>1][((wn&1)*64 + (qb)*32 + ni*16 + lr)*64]; \
      breg[ni][0] = *(const short8*)(p + colA0); \
      breg[ni][1] = *(const short8*)(p + colA1); } \
  } while(0)

#define MM(qa, qb, breg) do { \
    __builtin_amdgcn_s_setprio(1); \
    _Pragma("unroll") \
    for (int mi=0;mi<4;mi++) \
      _Pragma("unroll") \
      for (int ni=0;ni<2;ni++){ \
        acc[(qa)*4+mi][(qb)*2+ni] = __builtin_amdgcn_mfma_f32_16x16x32_bf16(a_[mi][0], breg[ni][0], acc[(qa)*4+mi][(qb)*2+ni],0,0,0); \
        acc[(qa)*4+mi][(qb)*2+ni] = __builtin_amdgcn_mfma_f32_16x16x32_bf16(a_[mi][1], breg[ni][1], acc[(qa)*4+mi][(qb)*2+ni],0,0,0); } \
    __builtin_amdgcn_s_setprio(0); \
  } while(0)

  // prologue: B(0), A(0) -> slot0; B(1) -> slot1   (12 loads; land first 8)
  STG(gBs, Bs, 0, 0, 0); STG(gBs, Bs, 0, 0, 1);
  STG(gAs, As, 0, 0, 0); STG(gAs, As, 0, 0, 1);
  STG(gBs, Bs, 1, 1, 0); STG(gBs, Bs, 1, 1, 1);
  VMC4; BARM;

  for (int k0 = 0; k0 < NKT; k0 += 2){
    const int k1 = k0 + 1;
    const int k2 = (k0+2 < NKT) ? k0+2 : 0;   // tail: dummy re-stage (dead data, masked)
    const int k3 = (k0+3 < NKT) ? k0+3 : 1;
    // ph1: quad(0,0) slot0 | stage A(k1)->slot1 h0
    RDA(0,0); RDB(0,0,b0_); STG(gAs, As, 1, k1, 0); BARM; MM(0,0,b0_); BARM;
    // ph2: quad(0,1) | stage A(k1)->slot1 h1
    RDB(0,1,b1_); STG(gAs, As, 1, k1, 1); BARM; MM(0,1,b1_); BARM;
    // ph3: quad(1,1) | stage B(k2)->slot0 h0
    RDA(0,1); STG(gBs, Bs, 0, k2, 0); BARM; MM(1,1,b1_); BARM;
    // ph4: quad(1,0) | stage B(k2)->slot0 h1 | vmcnt(4)
    STG(gBs, Bs, 0, k2, 1); BARM; MM(1,0,b0_); VMC4; BARM;
    // ph5: quad(0,0) slot1 | stage A(k2)->slot0 h0
    RDA(1,0); RDB(1,0,b0_); STG(gAs, As, 0, k2, 0); BARM; MM(0,0,b0_); BARM;
    // ph6: quad(0,1) | stage A(k2)->slot0 h1
    RDB(1,1,b1_); STG(gAs, As, 0, k2, 1); BARM; MM(0,1,b1_); BARM;
    // ph7: quad(1,1) | stage B(k3)->slot1 h0
    RDA(1,1); STG(gBs, Bs, 1, k3, 0); BARM; MM(1,1,b1_); BARM;
    // ph8: quad(1,0) | stage B(k3)->slot1 h1 | vmcnt(4)
    STG(gBs, Bs, 1, k3, 1); BARM; MM(1,0,b0_); VMC4; BARM;
  }
#undef STG
#undef RDA
#undef RDB
#undef MM

  if (MODE == 0){
    #pragma unroll
    for (int mi=0;mi<8;mi++){
      #pragma unroll
      for (int j=0;j<4;j++){
        int m = tm*256 + wm*128 + mi*16 + lg*4 + j;
        if (m < MTOT){
          #pragma unroll
          for (int ni=0;ni<4;ni++){
            int n = tn*256 + wn*64 + ni*16 + lr;
            if (n < NLIM) outF[(size_t)m*HD + n] = acc[mi][ni][j] + bias_q[n];
          }
        }
      }
    }
  } else {
    #pragma unroll
    for (int mi=0;mi<8;mi++){
      #pragma unroll
      for (int j=0;j<4;j++){
        int m = tm*256 + wm*128 + mi*16 + lg*4 + j;
        if (m >= MTOT) continue;
        int b = m / SEQ;
        int s = m - b*SEQ;
        #pragma unroll
        for (int ni=0;ni<4;ni++){
          int n = tn*256 + wn*64 + ni*16 + lr;
          if (n >= NLIM) continue;
          int mat = n / HD;
          int c = n - mat*HD;
          int h = c / DH;
          int d = c - h*DH;
          const float* bias = (mat==0) ? bias_q : (mat==1) ? bias_k : bias_v;
          float v = acc[mi][ni][j] + bias[c];
          int bh = b*NHD + h;
          if (mat == 0)      Qp[(size_t)bh*(SEQ*DHP) + (size_t)s*DHP + d] = f2bf(v*QSCALE);
          else if (mat == 1) Kp[(size_t)bh*(SP*DHP)  + (size_t)s*DHP + d] = f2bf(v);
          else               Vt[(size_t)bh*(VROWS*SP) + (size_t)d*SP + s] = f2bf(v);
        }
      }
    }
  }
}

// ---------------- PV sub-tile: pack P (in-register) -> bf16 frags, 6 MFMAs ----------------
__device__ __forceinline__ void pv_subtile(const f32x16 s, const us* __restrict__ vcol,
                                           int hi, f32x16 (&o)[3]){
  unsigned A[4], B[4], xA[4], xB[4];
  #pragma unroll
  for (int g=0; g<4; g++){
    A[g]  = cvtpk_bf16(s[4*g+0], s[4*g+1]);
    B[g]  = cvtpk_bf16(s[4*g+2], s[4*g+3]);
    xA[g] = (unsigned)__shfl_xor((int)A[g], 32);
    xB[g] = (unsigned)__shfl_xor((int)B[g], 32);
  }
  __builtin_amdgcn_s_setprio(1);
  #pragma unroll
  for (int ks=0; ks<2; ks++){
    unsigned w0 = hi ? xA[2*ks+1] : A[2*ks];
    unsigned w1 = hi ? xB[2*ks+1] : B[2*ks];
    unsigned w2 = hi ? A[2*ks+1]  : xA[2*ks];
    unsigned w3 = hi ? B[2*ks+1]  : xB[2*ks];
    u32x4 pw = {w0, w1, w2, w3};
    short8 pa = __builtin_bit_cast(short8, pw);
    #pragma unroll
    for (int dt=0; dt<3; dt++){
      short8 vf = *(const short8*)(vcol + (size_t)(dt*32)*SP + ks*16 + hi*8);
      o[dt] = __builtin_amdgcn_mfma_f32_32x32x16_bf16(pa, vf, o[dt], 0, 0, 0);
    }
  }
  __builtin_amdgcn_s_setprio(0);
}

// ---------------- fused attention: 32 q-rows/wave, swapped QK^T, in-register softmax ----------------
__global__ __launch_bounds__(256) void attn_kernel(
    const us* __restrict__ Qp, const us* __restrict__ Kp,
    const us* __restrict__ Vt, us* __restrict__ ctx)
{
  const int blk = blockIdx.x;            // 0..1535
  const int xcd = blk & 7, ii = blk >> 3;
  const int bh  = xcd*32 + ii/6;
  const int qt6 = ii % 6;
  const int tid = threadIdx.x, w = tid>>6, l = tid&63;
  const int lane = l & 31, hi = l >> 5;

  const int qbase = (qt6*4 + w)*32;
  if (qbase >= SEQ) return;

  const us* Qb = Qp + (size_t)bh*(SEQ*DHP);
  const us* Kb = Kp + (size_t)bh*(SP*DHP);
  const us* Vb = Vt + (size_t)bh*(VROWS*SP);

  int qr = qbase + lane; if (qr > SEQ-1) qr = SEQ-1;
  short8 qf[5];
  #pragma unroll
  for (int c=0;c<5;c++) qf[c] = *(const short8*)(Qb + (size_t)qr*DHP + c*16 + hi*8);

  f32x16 o[3];
  #pragma unroll
  for (int dt=0; dt<3; dt++)
    #pragma unroll
    for (int r=0;r<16;r++) o[dt][r] = 0.f;

  float m = -1e30f, lsum = 0.f;

  for (int kt=0; kt<12; kt++){
    const int kb = kt*64;
    f32x16 s0, s1;
    #pragma unroll
    for (int r=0;r<16;r++){ s0[r]=0.f; s1[r]=0.f; }

    const us* krow0 = Kb + (size_t)(kb + lane)*DHP + hi*8;
    __builtin_amdgcn_s_setprio(1);
    #pragma unroll
    for (int c=0;c<5;c++){
      short8 kf = *(const short8*)(krow0 + c*16);
      s0 = __builtin_amdgcn_mfma_f32_32x32x16_bf16(kf, qf[c], s0, 0, 0, 0);
    }
    __builtin_amdgcn_s_setprio(0);
    if (kt < 11){
      const us* krow1 = krow0 + 32*DHP;
      __builtin_amdgcn_s_setprio(1);
      #pragma unroll
      for (int c=0;c<5;c++){
        short8 kf = *(const short8*)(krow1 + c*16);
        s1 = __builtin_amdgcn_mfma_f32_32x32x16_bf16(kf, qf[c], s1, 0, 0, 0);
      }
      __builtin_amdgcn_s_setprio(0);
    } else {
      #pragma unroll
      for (int r=0;r<16;r++){
        const int base = 704 + (r&3) + 8*(r>>2);
        s0[r] = (base + 4*hi >= SEQ) ? -1e30f : s0[r];
        s1[r] = -1e30f;
      }
    }

    float tmax = -1e30f;
    #pragma unroll
    for (int r=0;r<16;r++) tmax = fmaxf(tmax, fmaxf(s0[r], s1[r]));
    tmax = fmaxf(tmax, __shfl_xor(tmax, 32));

    if (!__all(tmax <= m + 8.0f)){       // T13 defer-max (exp2 domain, THR=8)
      float mn = fmaxf(m, tmax);
      float sc = exp2f(m - mn);
      m = mn;
      lsum *= sc;
      #pragma unroll
      for (int dt=0; dt<3; dt++)
        #pragma unroll
        for (int r=0;r<16;r++) o[dt][r] *= sc;
    }

    float su = 0.f;
    #pragma unroll
    for (int r=0;r<16;r++){ float p = exp2f(s0[r]-m); s0[r]=p; su += p; }
    #pragma unroll
    for (int r=0;r<16;r++){ float p = exp2f(s1[r]-m); s1[r]=p; su += p; }
    su += __shfl_xor(su, 32);
    lsum += su;

    const us* vcol = Vb + (size_t)lane*SP + kb;
    pv_subtile(s0, vcol, hi, o);
    if (kt < 11) pv_subtile(s1, vcol + 32, hi, o);
  }

  float linv = 1.0f / lsum;
  const int b = bh >> 4, h = bh & 15;
  #pragma unroll
  for (int r=0;r<16;r++){
    const int qloc = (r&3) + 8*(r>>2) + 4*hi;
    float lv = __shfl(linv, qloc);
    int q = qbase + qloc;
    if (q < SEQ){
      us* crow = ctx + ((size_t)(b*SEQ + q))*HD + h*DH;
      #pragma unroll
      for (int dt=0; dt<3; dt++){
        int d = dt*32 + lane;
        if (d < DH) crow[d] = f2bf(o[dt][r] * lv);
      }
    }
  }
}

// ---------------- launcher ----------------
extern "C" void kernel_launch(void* const* d_in, const int* in_sizes, int n_in,
                              void* d_out, int out_size, void* d_ws, size_t ws_size,
                              hipStream_t stream) {
  const float* hs = (const float*)d_in[0];
  const float* Wq = (const float*)d_in[1]; const float* bq = (const float*)d_in[2];
  const float* Wk = (const float*)d_in[3]; const float* bk = (const float*)d_in[4];
  const float* Wv = (const float*)d_in[5]; const float* bv = (const float*)d_in[6];
  const float* Wo = (const float*)d_in[7]; const float* bo = (const float*)d_in[8];
  float* out = (float*)d_out;
  char* ws = (char*)d_ws;
  if (ws_size < WS_END) return;

  us* hsb   = (us*)(ws + OFF_HSB);  // later reused as ctx
  us* wqkvT = (us*)(ws + OFF_WQKV);
  us* woT   = (us*)(ws + OFF_WO);
  us* Qp    = (us*)(ws + OFF_Q);
  us* Kp    = (us*)(ws + OFF_K);
  us* Vt    = (us*)(ws + OFF_V);
  us* ctx   = hsb;

  // 1. convert hidden states to bf16
  int n4 = MTOT*HD/4;
  cvt_hs_kernel<<<(n4+255)/256, 256, 0, stream>>>(hs, hsb, n4);

  // 2. weights: transpose + convert to bf16 (n-major)
  dim3 bt(32, 8), gt(HD/32, HD/32);
  wt_cvt_kernel<<<gt, bt, 0, stream>>>(Wq, wqkvT);
  wt_cvt_kernel<<<gt, bt, 0, stream>>>(Wk, wqkvT + (size_t)HD*HD);
  wt_cvt_kernel<<<gt, bt, 0, stream>>>(Wv, wqkvT + (size_t)2*HD*HD);
  wt_cvt_kernel<<<gt, bt, 0, stream>>>(Wo, woT);

  // 3. zero Q only (d-pads 72..79 must be 0 vs K's garbage pads)
  hipMemsetAsync(ws + OFF_Q, 0, Q_BYTES, stream);

  // 4. QKV projection GEMM (256x256 8-phase), scatter epilogue
  gemm256_kernel<1><<<46*14, 512, 0, stream>>>(hsb, wqkvT, bq, bk, bv,
                                               nullptr, Qp, Kp, Vt);

  // 5. fused attention -> ctx [MTOT][1152] bf16 (reuses hsb buffer)
  attn_kernel<<<1536, 256, 0, stream>>>(Qp, Kp, Vt, ctx);

  // 6. output projection GEMM -> fp32 out + bo
  gemm256_kernel<0><<<46*5, 512, 0, stream>>>(ctx, woT, bo, nullptr, nullptr,
                                              out, nullptr, nullptr, nullptr);
}